// Round 6
// baseline (131.297 us; speedup 1.0000x reference)
//
#include <hip/hip_runtime.h>
#include <hip/hip_fp16.h>

// out[e] = dot(h[src[e]], h[dst[e]]), D=128, N=100k, E=600k.
// h staged as fp16 in d_ws (row 256B, footprint 25.6MB). 16 lanes/edge:
// each lane reads ONE uint4 (8 halves) per row -> full row = one coalesced
// 256B segment. 4-edge unroll = 8 independent row loads in flight per lane
// (latency-bound regime per round-4 counters: 3.3 TB/s eff, VALU 14%).
// fp32 accumulate via fdot2; 4x shfl_xor reduce within the 16-lane group.

constexpr int D   = 128;
constexpr int LPE = 16;   // lanes per edge
constexpr int UNR = 4;    // edges in flight per slot

// ---------- conversion: h (fp32) -> hh (fp16) ----------
__global__ __launch_bounds__(256) void convert_kernel(
    const float* __restrict__ h, __half* __restrict__ hh, int n4)
{
    const int stride = gridDim.x * blockDim.x;
    for (int k = blockIdx.x * blockDim.x + threadIdx.x; k < n4; k += stride) {
        float4 v = reinterpret_cast<const float4*>(h)[k];
        __half2 a = __floats2half2_rn(v.x, v.y);
        __half2 b = __floats2half2_rn(v.z, v.w);
        uint2 packed;
        packed.x = *reinterpret_cast<unsigned int*>(&a);
        packed.y = *reinterpret_cast<unsigned int*>(&b);
        reinterpret_cast<uint2*>(hh)[k] = packed;
    }
}

#if defined(__has_builtin) && __has_builtin(__builtin_amdgcn_fdot2)
#define HAS_FDOT2 1
#else
#define HAS_FDOT2 0
#endif

__device__ __forceinline__ float dot8(uint4 ua, uint4 ub)
{
    float acc = 0.f;
    const unsigned int* pa = &ua.x;
    const unsigned int* pb = &ub.x;
#pragma unroll
    for (int i = 0; i < 4; ++i) {
        __half2 ha = *reinterpret_cast<const __half2*>(&pa[i]);
        __half2 hb = *reinterpret_cast<const __half2*>(&pb[i]);
#if HAS_FDOT2
        acc = __builtin_amdgcn_fdot2(*reinterpret_cast<_Float16_2*>(&ha),
                                     *reinterpret_cast<_Float16_2*>(&hb),
                                     acc, false);
#else
        float2 fa = __half22float2(ha);
        float2 fb = __half22float2(hb);
        acc = fmaf(fa.x, fb.x, acc);
        acc = fmaf(fa.y, fb.y, acc);
#endif
    }
    return acc;
}

__device__ __forceinline__ float reduce16(float acc)
{
    acc += __shfl_xor(acc, 1);
    acc += __shfl_xor(acc, 2);
    acc += __shfl_xor(acc, 4);
    acc += __shfl_xor(acc, 8);
    return acc;
}

// ---------- fp16 gather kernel ----------
__global__ __launch_bounds__(256) void edge_dot_f16_kernel(
    const __half* __restrict__ hh,
    const int*    __restrict__ src,
    const int*    __restrict__ dst,
    float*        __restrict__ out,
    int E)
{
    const int tid    = blockIdx.x * blockDim.x + threadIdx.x;
    const int sub    = threadIdx.x & (LPE - 1);
    const int slot   = tid / LPE;
    const int nslots = (gridDim.x * blockDim.x) / LPE;
    const int step   = UNR * nslots;

    int e = slot;
    int s[UNR], t[UNR];
    if (e + (UNR - 1) * nslots < E) {
#pragma unroll
        for (int k = 0; k < UNR; ++k) {
            s[k] = src[e + k * nslots];
            t[k] = dst[e + k * nslots];
        }
    }

    while (e + (UNR - 1) * nslots < E) {
        // 8 independent 16B row loads in flight.
        uint4 a[UNR], b[UNR];
#pragma unroll
        for (int k = 0; k < UNR; ++k) {
            a[k] = *(reinterpret_cast<const uint4*>(hh + (size_t)s[k] * D) + sub);
            b[k] = *(reinterpret_cast<const uint4*>(hh + (size_t)t[k] * D) + sub);
        }

        const int en = e + step;
        // Prefetch next iteration's indices while row loads are in flight.
        if (en + (UNR - 1) * nslots < E) {
#pragma unroll
            for (int k = 0; k < UNR; ++k) {
                s[k] = src[en + k * nslots];
                t[k] = dst[en + k * nslots];
            }
        }

#pragma unroll
        for (int k = 0; k < UNR; ++k) {
            float acc = reduce16(dot8(a[k], b[k]));
            if (sub == 0) out[e + k * nslots] = acc;
        }
        e = en;
    }

    // Tail: up to UNR-1 edges per slot.
    for (; e < E; e += nslots) {
        const int ss = src[e];
        const int tt = dst[e];
        uint4 a = *(reinterpret_cast<const uint4*>(hh + (size_t)ss * D) + sub);
        uint4 b = *(reinterpret_cast<const uint4*>(hh + (size_t)tt * D) + sub);
        float acc = reduce16(dot8(a, b));
        if (sub == 0) out[e] = acc;
    }
}

// ---------- fp32 fallback (no ws) ----------
__global__ __launch_bounds__(256) void edge_dot_f32_kernel(
    const float* __restrict__ h,
    const int*   __restrict__ src,
    const int*   __restrict__ dst,
    float*       __restrict__ out,
    int E)
{
    const int tid    = blockIdx.x * blockDim.x + threadIdx.x;
    const int sub    = threadIdx.x & (LPE - 1);
    const int slot   = tid / LPE;
    const int nslots = (gridDim.x * blockDim.x) / LPE;
    const int off    = sub * 2;

    for (int e = slot; e < E; e += nslots) {
        const int s = src[e];
        const int t = dst[e];
        const float4* hu = reinterpret_cast<const float4*>(h + (size_t)s * D) + off;
        const float4* hv = reinterpret_cast<const float4*>(h + (size_t)t * D) + off;
        float4 a0 = hu[0]; float4 a1 = hu[1];
        float4 b0 = hv[0]; float4 b1 = hv[1];
        float acc = a0.x * b0.x + a0.y * b0.y + a0.z * b0.z + a0.w * b0.w
                  + a1.x * b1.x + a1.y * b1.y + a1.z * b1.z + a1.w * b1.w;
        acc = reduce16(acc);
        if (sub == 0) out[e] = acc;
    }
}

extern "C" void kernel_launch(void* const* d_in, const int* in_sizes, int n_in,
                              void* d_out, int out_size, void* d_ws, size_t ws_size,
                              hipStream_t stream) {
    const float* h   = (const float*)d_in[0];
    const int*   src = (const int*)d_in[1];
    const int*   dst = (const int*)d_in[2];
    float*       out = (float*)d_out;

    const int hN = in_sizes[0];     // N*D floats
    const int E  = in_sizes[1];     // edges

    const int block = 256;
    int grid = (E + (block / LPE) - 1) / (block / LPE);
    if (grid > 2048) grid = 2048;

    const size_t need = (size_t)hN * sizeof(__half);
    if (ws_size >= need) {
        __half* hh = (__half*)d_ws;
        convert_kernel<<<2048, 256, 0, stream>>>(h, hh, hN / 4);
        edge_dot_f16_kernel<<<grid, block, 0, stream>>>(hh, src, dst, out, E);
    } else {
        edge_dot_f32_kernel<<<grid, block, 0, stream>>>(h, src, dst, out, E);
    }
}